// Round 14
// baseline (6869.785 us; speedup 1.0000x reference)
//
#include <hip/hip_runtime.h>

// HighwayLayerDiscrete: 256-step recurrent highway net, batch 64, units 1024.
// Phase P = t*4+p: p0: h=lrelu(y@w_y + xproj[t]); p1/p2: h=lrelu(h@w_h[l]+b_h[l]);
// p3: y += h@w_out + b_out; out[:,t,:]=y.
//
// R21 = R20 (proven best, 6.18 ms) + PER-WAVE ACQUIRE: the post-poll
// __syncthreads existed only to broadcast wave0's flag observation to the
// other 7 waves. Flags are MONOTONE, so each wave polls independently (all
// 64 lanes read the same 32 producer flags; lanes 32-63 duplicate 0-31;
// __all over the wave; per-thread asm clobber orders stage loads after the
// observation). Barriers/phase 4 -> 3, and the observe->barrier->wake
// serialization is gone. Staging is BYTE-IDENTICAL to R20 (R8's regression
// came from scattered staging, not per-wave polling per se).
// R20 wins kept: red2 de-aliased (no compute->red2 alias barrier); biases
// hoisted to registers. R13 wins kept: per-producer flag STORES + coalesced
// 32-flag poll (bounded 2^20); xpre/ypre finalize-operand prefetch;
// p3 out-store deferred past the flag post.
// Dead ends (do not revisit): z-state refold (R14-R19: w_ow blows the 4MB
// per-XCD L2 -> FETCH x6); asm-forced W residency (R11: scratch spill);
// shfl pre-reduction (R12); sc0/L2-tier exchange (R9: DEADLOCK); cross-WG
// split-K (R2/R3); >256 blocks (R4); cache fences (R1); two wreg reload
// sites (R16: live-doubling -> 113GB spill).
// Release chain (unchanged, proven): finalize llc_stores -> waitcnt0 +
// barrier -> tid0 flag store. Acquire: per-wave poll + clobber. LDS skew
// injective (R5).

constexpr int B = 64, T = 256, U = 1024, E = 512;
constexpr int BU = B * U;     // 65536
constexpr int APITCH = 1156;  // A-row pitch (1024 + 36-skew; ==4 mod 8)
constexpr int RPITCH = 264;   // red2 per-s pitch

#define LRELU(v) ((v) > 0.f ? (v) : 0.2f * (v))

using f4 = float __attribute__((ext_vector_type(4)));

__device__ __forceinline__ unsigned long long llc_load64(const float* p) {
  return __hip_atomic_load((const unsigned long long*)p, __ATOMIC_RELAXED,
                           __HIP_MEMORY_SCOPE_AGENT);
}
__device__ __forceinline__ void llc_store(float* p, float v) {
  __hip_atomic_store(p, v, __ATOMIC_RELAXED, __HIP_MEMORY_SCOPE_AGENT);
}
__device__ __forceinline__ unsigned llc_flag(const unsigned* p) {
  return __hip_atomic_load(p, __ATOMIC_RELAXED, __HIP_MEMORY_SCOPE_AGENT);
}
__device__ __forceinline__ void llc_flag_store(unsigned* p, unsigned v) {
  __hip_atomic_store(p, v, __ATOMIC_RELAXED, __HIP_MEMORY_SCOPE_AGENT);
}

// ---------------- init: zero flags, y0 into slot1 and ybuf ----------------
__global__ void k_init(float* __restrict__ slot1, float* __restrict__ ybuf,
                       const float* __restrict__ h0,
                       unsigned* __restrict__ flags) {
  int tid = blockIdx.x * 256 + threadIdx.x;
  if (tid < 512) flags[tid] = 0u;
  if (tid < BU) {
    float v = h0[tid & (U - 1)];
    slot1[tid] = v;
    ybuf[tid] = v;
  }
}

// ------- xproj[t*64+n][u] = emb[x[n][t]] @ w_x + b_in (R2/R3-proven) -------
__global__ __launch_bounds__(256) void k_xproj(
    const int* __restrict__ x, const float* __restrict__ emb,
    const float* __restrict__ w_x, const float* __restrict__ b_in,
    float* __restrict__ xp) {
  __shared__ float a_s[64][36];
  __shared__ float w_s[32][64];
  __shared__ int idxs[64];
  const int tid = threadIdx.x;
  const int m0 = blockIdx.x * 64;
  const int c0 = blockIdx.y * 64;
  if (tid < 64) {
    int m = m0 + tid;
    idxs[tid] = x[(m & 63) * T + (m >> 6)];  // x[n][t], row m = t*64+n
  }
  __syncthreads();
  const int rq = tid >> 4, cq = tid & 15;
  float acc[4][4] = {};
  for (int k0 = 0; k0 < E; k0 += 32) {
#pragma unroll
    for (int rep = 0; rep < 8; ++rep) {
      int e = rep * 256 + tid;
      int r = e >> 5, k = e & 31;
      a_s[r][k] = emb[(size_t)idxs[r] * E + k0 + k];
    }
#pragma unroll
    for (int rep = 0; rep < 2; ++rep) {
      int e = rep * 256 + tid;
      int kr = e >> 4, q = e & 15;
      *(float4*)&w_s[kr][4 * q] =
          *(const float4*)(w_x + (size_t)(k0 + kr) * U + c0 + 4 * q);
    }
    __syncthreads();
#pragma unroll
    for (int kc = 0; kc < 32; kc += 4) {
      float4 a4[4], w4[4];
#pragma unroll
      for (int i = 0; i < 4; ++i) a4[i] = *(const float4*)&a_s[4 * rq + i][kc];
#pragma unroll
      for (int kk = 0; kk < 4; ++kk)
        w4[kk] = *(const float4*)&w_s[kc + kk][4 * cq];
#pragma unroll
      for (int i = 0; i < 4; ++i) {
        const float av[4] = {a4[i].x, a4[i].y, a4[i].z, a4[i].w};
#pragma unroll
        for (int kk = 0; kk < 4; ++kk) {
          acc[i][0] += av[kk] * w4[kk].x;
          acc[i][1] += av[kk] * w4[kk].y;
          acc[i][2] += av[kk] * w4[kk].z;
          acc[i][3] += av[kk] * w4[kk].w;
        }
      }
    }
    __syncthreads();
  }
  const float4 bb = *(const float4*)(b_in + c0 + 4 * cq);
  const float bv[4] = {bb.x, bb.y, bb.z, bb.w};
#pragma unroll
  for (int i = 0; i < 4; ++i) {
    float4 o;
    o.x = acc[i][0] + bv[0];
    o.y = acc[i][1] + bv[1];
    o.z = acc[i][2] + bv[2];
    o.w = acc[i][3] + bv[3];
    *(float4*)(xp + (size_t)(m0 + 4 * rq + i) * U + c0 + 4 * cq) = o;
  }
}

// ---------------- sequential pipeline ----------------
// 256 WGs = 8 rg x 32 cg (XCD = cg&7, L2-affine). Thread (s,ri,ci): K-slice
// [32s,32s+32), rows [4ri,4ri+4) of 8, cols [4ci,4ci+4) of 32. Partials ->
// red2[s][out] pitch 264 (separate buffer). Barriers/phase: stage-bar, B1,
// drain-bar (poll is now per-wave, barrier-free).
__global__ __launch_bounds__(512, 2) void k_seq(
    const float* __restrict__ xp, const float* __restrict__ w_y,
    const float* __restrict__ w_h, const float* __restrict__ b_h,
    const float* __restrict__ w_out, const float* __restrict__ b_out,
    float* __restrict__ out, float* __restrict__ slots,
    float* __restrict__ ybuf, unsigned* __restrict__ flags) {
  __shared__ float a_s[8 * APITCH];    // 9248 floats = 36992 B
  __shared__ float red2[32 * RPITCH];  // 8448 floats = 33792 B (de-aliased)
  const int tid = threadIdx.x;
  const int cg = blockIdx.x & 31, rg = blockIdx.x >> 5;
  const int l = tid & 63;
  const int ci = l & 7, ri = (l >> 3) & 1;
  const int s = (tid >> 6) * 4 + ((l >> 4) & 3);
  const int cb = 4 * ci, r0 = 4 * ri, k0 = 32 * s;
  unsigned* const myflag = &flags[rg * 32 + cg];
  const unsigned* const pollf = &flags[rg * 32 + (l & 31)];
  // finalize coordinates + hoisted loop-invariant operands (valid tid<256)
  const int frow = 8 * rg + (tid >> 5);
  const int fu = 32 * cg + (tid & 31);
  const size_t fyi = (size_t)frow * U + fu;
  const float bh0r = b_h[fu], bh1r = b_h[U + fu], bor = b_out[fu];

  // W base selector for phase P
  auto wbase = [&](int P) -> const float* {
    const int p = P & 3;
    const float* Wsrc = (p == 0)   ? w_y
                        : (p == 3) ? w_out
                                   : w_h + (size_t)(p - 1) * U * U;
    return Wsrc + (size_t)k0 * U + 32 * cg + cb;
  };
  // ---- W prefetch for P=0 (static addresses -> latency off critical path) --
  f4 wreg[32];  // W[k0+j][cb..cb+4), j=0..31
  {
    const float* wp = wbase(0);
#pragma unroll
    for (int j = 0; j < 32; ++j) wreg[j] = *(const f4*)(wp + (size_t)j * U);
  }

  for (int P = 0; P < 4 * T; ++P) {
    const int t = P >> 2, p = P & 3;
    const float* Asrc =
        slots + (size_t)((P + 1) & 1) * BU + (size_t)(8 * rg) * U;
    float* slotw = slots + (size_t)(P & 1) * BU;
    // ---- 0. finalize-operand prefetch (phase-start-known, WG-private /
    //         precomputed; latency hides under poll + stage) ----
    float xpre = 0.f, ypre = 0.f;
    if (tid < 256) {
      if (p == 0) xpre = xp[((size_t)t * B + frow) * U + fu];
      else if (p == 3) ypre = ybuf[fyi];
    }
    float yout = 0.f;  // deferred p3 out-store
    size_t oidx = 0;
    int do_out = 0;
    // ---- 1. acquire: PER-WAVE poll, barrier-free. Every wave's 64 lanes
    //         read the 32 producer flags (lanes 32-63 duplicate 0-31),
    //         exit on __all(f>=P). Flags are monotone -> no broadcast
    //         barrier needed; per-thread clobber orders the stage loads.
    //         Bounded for container safety. ----
    if (P > 0) {
      const unsigned tg = (unsigned)P;
      for (int it = 0; it < (1 << 20); ++it) {
        unsigned f = llc_flag(pollf);
        if (__all((int)(f >= tg))) break;
        __builtin_amdgcn_s_sleep(1);
      }
      asm volatile("" ::: "memory");
    }
    // ---- 2. stage A: 8 rows x 1024, 8B sc1 loads -> single b128 LDS write --
#pragma unroll
    for (int rep = 0; rep < 4; ++rep) {
      int idx4 = 512 * rep + tid;  // f4 index in [0,2048)
      int row = idx4 >> 8, kq = idx4 & 255, k = 4 * kq;
      const float* pa = Asrc + (size_t)row * U + k;
      unsigned long long v0 = llc_load64(pa);
      unsigned long long v1 = llc_load64(pa + 2);
      f4 v;
      ((unsigned long long*)&v)[0] = v0;
      ((unsigned long long*)&v)[1] = v1;
      *(f4*)&a_s[row * APITCH + 36 * (k >> 5) + (k & 31)] = v;
    }
    __syncthreads();  // stage-bar: all LDS writes visible before compute
    // ---- 3. main: 4x4x(K=32) tile; A from LDS, W from registers ----
    f4 acc[4];
#pragma unroll
    for (int i = 0; i < 4; ++i) acc[i] = (f4){0.f, 0.f, 0.f, 0.f};
    {
      const int abase = r0 * APITCH + 36 * s;  // 36*(k0>>5) = 36s
#pragma unroll
      for (int q = 0; q < 8; ++q) {
        const int ai = abase + 4 * q;
        f4 a0 = *(const f4*)&a_s[ai];
        f4 a1 = *(const f4*)&a_s[ai + APITCH];
        f4 a2 = *(const f4*)&a_s[ai + 2 * APITCH];
        f4 a3 = *(const f4*)&a_s[ai + 3 * APITCH];
        const f4 w0 = wreg[4 * q], w1 = wreg[4 * q + 1];
        const f4 w2 = wreg[4 * q + 2], w3 = wreg[4 * q + 3];
        acc[0] += a0.x * w0 + a0.y * w1 + a0.z * w2 + a0.w * w3;
        acc[1] += a1.x * w0 + a1.y * w1 + a1.z * w2 + a1.w * w3;
        acc[2] += a2.x * w0 + a2.y * w1 + a2.z * w2 + a2.w * w3;
        acc[3] += a3.x * w0 + a3.y * w1 + a3.z * w2 + a3.w * w3;
      }
    }
    // ---- 4. write partials red2[s*264 + out], b128 (de-aliased: no
    //         pre-barrier; prev finalize reads sealed by drain-bar) ----
#pragma unroll
    for (int i = 0; i < 4; ++i)
      *(f4*)&red2[s * RPITCH + (r0 + i) * 32 + cb] = acc[i];
    __syncthreads();  // B1: all partials visible
    // ---- 5. finalize: 256 threads, sum 32 partials, bias+act, store ----
    if (tid < 256) {
      float sum = 0.f;
#pragma unroll
      for (int z = 0; z < 32; ++z) sum += red2[z * RPITCH + tid];
      if (p == 0) {
        float v = sum + xpre;
        llc_store(slotw + fyi, LRELU(v));
      } else if (p < 3) {
        float v = sum + (p == 1 ? bh0r : bh1r);
        llc_store(slotw + fyi, LRELU(v));
      } else {
        float yn = ypre + sum + bor;  // ybuf prefetched at phase start
        ybuf[fyi] = yn;
        llc_store(slotw + fyi, yn);  // y is next p0's A
        yout = yn;                   // out[] store deferred past flag post
        oidx = ((size_t)frow * T + t) * U + fu;
        do_out = 1;
      }
    }
    // ---- 6. drain: exchange stores at LLC before the flag post ----
    asm volatile("" ::: "memory");
    __builtin_amdgcn_s_waitcnt(0);
    __syncthreads();  // drain-bar: flag post ordered after ALL store acks
    // ---- 7. W prefetch for P+1 (single reload site; overlaps post + poll
    //         + next stage) ----
    if (P < 4 * T - 1) {
      const float* wp = wbase(P + 1);
#pragma unroll
      for (int j = 0; j < 32; ++j) wreg[j] = *(const f4*)(wp + (size_t)j * U);
    }
    // ---- 8. release: per-producer flag store (no RMW serialization) ----
    if (tid == 0) llc_flag_store(myflag, (unsigned)(P + 1));
    // ---- 9. deferred p3 out-store (HBM ack off the flag critical path;
    //         next phase's waitcnt(0) absorbs it) ----
    if (do_out) out[oidx] = yout;
  }
}

extern "C" void kernel_launch(void* const* d_in, const int* in_sizes, int n_in,
                              void* d_out, int out_size, void* d_ws,
                              size_t ws_size, hipStream_t stream) {
  const int* x = (const int*)d_in[0];
  const float* emb = (const float*)d_in[1];
  const float* w_y = (const float*)d_in[2];
  const float* w_x = (const float*)d_in[3];
  const float* b_in = (const float*)d_in[4];
  const float* w_h = (const float*)d_in[5];
  const float* b_h = (const float*)d_in[6];
  const float* w_out = (const float*)d_in[7];
  const float* b_out = (const float*)d_in[8];
  const float* h0 = (const float*)d_in[9];
  float* out = (float*)d_out;

  // workspace (floats): xproj | slots[2] | ybuf | flags
  float* ws = (float*)d_ws;
  float* xpb = ws;                         // T*B*U
  float* slots = xpb + (size_t)T * B * U;  // 2*BU
  float* ybuf = slots + 2 * (size_t)BU;    // BU
  unsigned* flags = (unsigned*)(ybuf + (size_t)BU);  // 256 uints (512 zeroed)

  k_init<<<256, 256, 0, stream>>>(slots + (size_t)BU, ybuf, h0, flags);
  dim3 g1(256, 16);
  k_xproj<<<g1, 256, 0, stream>>>(x, emb, w_x, b_in, xpb);

  void* args[] = {&xpb,   &w_y, &w_h,   &b_h,  &w_out,
                  &b_out, &out, &slots, &ybuf, &flags};
  hipLaunchCooperativeKernel((void*)k_seq, dim3(256), dim3(512), args, 0u,
                             stream);
}

// Round 15
// 6176.431 us; speedup vs baseline: 1.1123x; 1.1123x over previous
//
#include <hip/hip_runtime.h>

// HighwayLayerDiscrete: 256-step recurrent highway net, batch 64, units 1024.
// Phase P = t*4+p: p0: h=lrelu(y@w_y + xproj[t]); p1/p2: h=lrelu(h@w_h[l]+b_h[l]);
// p3: y += h@w_out + b_out; out[:,t,:]=y.
//
// R22 = R20 RESTORED (verified best, 6.18 ms) — FINAL. R21's per-wave
// acquire regressed (6.87 ms): 8 waves x 256 WGs spinning on the same flag
// line = 8x LLC poll traffic + 8 observe-latencies, and the WG reconverges
// at the stage-bar anyway. Fourth confirmation (R8/R11/R12/R21) that ANY
// perturbation of the single-observer/barrier-broadcast protocol regresses.
//
// STRUCTURAL FLOOR (why this is final): 1024 truly-serial cross-WG phases
// (4 layers x 256 steps; each next-phase input = full prev-phase output).
// Per-phase floor = flag observe (LLC RT) -> A-stage (LLC RT) -> compute
// (~1.6us VALU) -> reduce -> store-ack drain  ~= 6.0us; measured 6.04us.
// Latency-bound recurrence: HBM 3%, VALU 26% -- no roofline denominator.
// Remaining levers all measured-regressive or banned:
//   restructures (R8 per-wave stage, R11 asm W-prefetch, R12 shfl reduce,
//   R18 fused dual-GEMM, R21 per-wave poll) -- all slower;
//   z-state refold (R14-R19): w_ow panel blows 4MB/XCD L2, FETCH x6;
//   sc0/L2-tier exchange (R9): DEADLOCK; cross-WG split-K (R2/R3): LLC wall;
//   >256 blocks (R4): silent fail; cache fences (R1): 66 ms.
// R20 edits kept: red2 de-aliased (alias barrier removed; 4 barriers/phase
// -> poll-bar, stage-bar, B1, drain-bar); biases hoisted to registers.
// R13 edits kept: per-producer flag STORES + coalesced 32-flag poll
// (bounded 2^20); xpre/ypre finalize-operand prefetch; p3 out-store
// deferred past the flag post.
// Protocol (proven): release = finalize llc_stores -> waitcnt0 + barrier ->
// tid0 flag store; acquire = wave0 32-lane poll -> barrier -> asm clobber;
// all cross-WG data relaxed agent-scope (sc1/LLC); LDS skew injective (R5);
// single wreg reload site (R16: two sites -> live-doubling -> 113GB spill).

constexpr int B = 64, T = 256, U = 1024, E = 512;
constexpr int BU = B * U;     // 65536
constexpr int APITCH = 1156;  // A-row pitch (1024 + 36-skew; ==4 mod 8)
constexpr int RPITCH = 264;   // red2 per-s pitch

#define LRELU(v) ((v) > 0.f ? (v) : 0.2f * (v))

using f4 = float __attribute__((ext_vector_type(4)));

__device__ __forceinline__ unsigned long long llc_load64(const float* p) {
  return __hip_atomic_load((const unsigned long long*)p, __ATOMIC_RELAXED,
                           __HIP_MEMORY_SCOPE_AGENT);
}
__device__ __forceinline__ void llc_store(float* p, float v) {
  __hip_atomic_store(p, v, __ATOMIC_RELAXED, __HIP_MEMORY_SCOPE_AGENT);
}
__device__ __forceinline__ unsigned llc_flag(const unsigned* p) {
  return __hip_atomic_load(p, __ATOMIC_RELAXED, __HIP_MEMORY_SCOPE_AGENT);
}
__device__ __forceinline__ void llc_flag_store(unsigned* p, unsigned v) {
  __hip_atomic_store(p, v, __ATOMIC_RELAXED, __HIP_MEMORY_SCOPE_AGENT);
}

// ---------------- init: zero flags, y0 into slot1 and ybuf ----------------
__global__ void k_init(float* __restrict__ slot1, float* __restrict__ ybuf,
                       const float* __restrict__ h0,
                       unsigned* __restrict__ flags) {
  int tid = blockIdx.x * 256 + threadIdx.x;
  if (tid < 512) flags[tid] = 0u;
  if (tid < BU) {
    float v = h0[tid & (U - 1)];
    slot1[tid] = v;
    ybuf[tid] = v;
  }
}

// ------- xproj[t*64+n][u] = emb[x[n][t]] @ w_x + b_in (R2/R3-proven) -------
__global__ __launch_bounds__(256) void k_xproj(
    const int* __restrict__ x, const float* __restrict__ emb,
    const float* __restrict__ w_x, const float* __restrict__ b_in,
    float* __restrict__ xp) {
  __shared__ float a_s[64][36];
  __shared__ float w_s[32][64];
  __shared__ int idxs[64];
  const int tid = threadIdx.x;
  const int m0 = blockIdx.x * 64;
  const int c0 = blockIdx.y * 64;
  if (tid < 64) {
    int m = m0 + tid;
    idxs[tid] = x[(m & 63) * T + (m >> 6)];  // x[n][t], row m = t*64+n
  }
  __syncthreads();
  const int rq = tid >> 4, cq = tid & 15;
  float acc[4][4] = {};
  for (int k0 = 0; k0 < E; k0 += 32) {
#pragma unroll
    for (int rep = 0; rep < 8; ++rep) {
      int e = rep * 256 + tid;
      int r = e >> 5, k = e & 31;
      a_s[r][k] = emb[(size_t)idxs[r] * E + k0 + k];
    }
#pragma unroll
    for (int rep = 0; rep < 2; ++rep) {
      int e = rep * 256 + tid;
      int kr = e >> 4, q = e & 15;
      *(float4*)&w_s[kr][4 * q] =
          *(const float4*)(w_x + (size_t)(k0 + kr) * U + c0 + 4 * q);
    }
    __syncthreads();
#pragma unroll
    for (int kc = 0; kc < 32; kc += 4) {
      float4 a4[4], w4[4];
#pragma unroll
      for (int i = 0; i < 4; ++i) a4[i] = *(const float4*)&a_s[4 * rq + i][kc];
#pragma unroll
      for (int kk = 0; kk < 4; ++kk)
        w4[kk] = *(const float4*)&w_s[kc + kk][4 * cq];
#pragma unroll
      for (int i = 0; i < 4; ++i) {
        const float av[4] = {a4[i].x, a4[i].y, a4[i].z, a4[i].w};
#pragma unroll
        for (int kk = 0; kk < 4; ++kk) {
          acc[i][0] += av[kk] * w4[kk].x;
          acc[i][1] += av[kk] * w4[kk].y;
          acc[i][2] += av[kk] * w4[kk].z;
          acc[i][3] += av[kk] * w4[kk].w;
        }
      }
    }
    __syncthreads();
  }
  const float4 bb = *(const float4*)(b_in + c0 + 4 * cq);
  const float bv[4] = {bb.x, bb.y, bb.z, bb.w};
#pragma unroll
  for (int i = 0; i < 4; ++i) {
    float4 o;
    o.x = acc[i][0] + bv[0];
    o.y = acc[i][1] + bv[1];
    o.z = acc[i][2] + bv[2];
    o.w = acc[i][3] + bv[3];
    *(float4*)(xp + (size_t)(m0 + 4 * rq + i) * U + c0 + 4 * cq) = o;
  }
}

// ---------------- sequential pipeline ----------------
// 256 WGs = 8 rg x 32 cg (XCD = cg&7, L2-affine). Thread (s,ri,ci): K-slice
// [32s,32s+32), rows [4ri,4ri+4) of 8, cols [4ci,4ci+4) of 32. Partials ->
// red2[s][out] pitch 264 (SEPARATE buffer). Barriers/phase: poll, stage,
// B1 (red2 ready), drain.
__global__ __launch_bounds__(512, 2) void k_seq(
    const float* __restrict__ xp, const float* __restrict__ w_y,
    const float* __restrict__ w_h, const float* __restrict__ b_h,
    const float* __restrict__ w_out, const float* __restrict__ b_out,
    float* __restrict__ out, float* __restrict__ slots,
    float* __restrict__ ybuf, unsigned* __restrict__ flags) {
  __shared__ float a_s[8 * APITCH];    // 9248 floats = 36992 B
  __shared__ float red2[32 * RPITCH];  // 8448 floats = 33792 B (de-aliased)
  const int tid = threadIdx.x;
  const int cg = blockIdx.x & 31, rg = blockIdx.x >> 5;
  const int l = tid & 63;
  const int ci = l & 7, ri = (l >> 3) & 1;
  const int s = (tid >> 6) * 4 + ((l >> 4) & 3);
  const int cb = 4 * ci, r0 = 4 * ri, k0 = 32 * s;
  unsigned* const myflag = &flags[rg * 32 + cg];
  const unsigned* const pollf = &flags[rg * 32 + (l & 31)];
  // finalize coordinates + hoisted loop-invariant operands (valid tid<256)
  const int frow = 8 * rg + (tid >> 5);
  const int fu = 32 * cg + (tid & 31);
  const size_t fyi = (size_t)frow * U + fu;
  const float bh0r = b_h[fu], bh1r = b_h[U + fu], bor = b_out[fu];

  // W base selector for phase P
  auto wbase = [&](int P) -> const float* {
    const int p = P & 3;
    const float* Wsrc = (p == 0)   ? w_y
                        : (p == 3) ? w_out
                                   : w_h + (size_t)(p - 1) * U * U;
    return Wsrc + (size_t)k0 * U + 32 * cg + cb;
  };
  // ---- W prefetch for P=0 (static addresses -> latency off critical path) --
  f4 wreg[32];  // W[k0+j][cb..cb+4), j=0..31
  {
    const float* wp = wbase(0);
#pragma unroll
    for (int j = 0; j < 32; ++j) wreg[j] = *(const f4*)(wp + (size_t)j * U);
  }

  for (int P = 0; P < 4 * T; ++P) {
    const int t = P >> 2, p = P & 3;
    const float* Asrc =
        slots + (size_t)((P + 1) & 1) * BU + (size_t)(8 * rg) * U;
    float* slotw = slots + (size_t)(P & 1) * BU;
    // ---- 0. finalize-operand prefetch (phase-start-known, WG-private /
    //         precomputed; latency hides under poll + stage) ----
    float xpre = 0.f, ypre = 0.f;
    if (tid < 256) {
      if (p == 0) xpre = xp[((size_t)t * B + frow) * U + fu];
      else if (p == 3) ypre = ybuf[fyi];
    }
    float yout = 0.f;  // deferred p3 out-store
    size_t oidx = 0;
    int do_out = 0;
    // ---- 1. acquire: wave0's 32 lanes read 32 producer flags (one 128B
    //         LLC transaction), __all(f>=P); bounded for container safety --
    if (P > 0) {
      if (tid < 64) {
        const unsigned tg = (unsigned)P;
        for (int it = 0; it < (1 << 20); ++it) {
          unsigned f = llc_flag(pollf);
          if (__all((int)(f >= tg))) break;
          __builtin_amdgcn_s_sleep(1);
        }
      }
      __syncthreads();
      asm volatile("" ::: "memory");
    }
    // ---- 2. stage A: 8 rows x 1024, 8B sc1 loads -> single b128 LDS write --
#pragma unroll
    for (int rep = 0; rep < 4; ++rep) {
      int idx4 = 512 * rep + tid;  // f4 index in [0,2048)
      int row = idx4 >> 8, kq = idx4 & 255, k = 4 * kq;
      const float* pa = Asrc + (size_t)row * U + k;
      unsigned long long v0 = llc_load64(pa);
      unsigned long long v1 = llc_load64(pa + 2);
      f4 v;
      ((unsigned long long*)&v)[0] = v0;
      ((unsigned long long*)&v)[1] = v1;
      *(f4*)&a_s[row * APITCH + 36 * (k >> 5) + (k & 31)] = v;
    }
    __syncthreads();
    // ---- 3. main: 4x4x(K=32) tile; A from LDS, W from registers ----
    f4 acc[4];
#pragma unroll
    for (int i = 0; i < 4; ++i) acc[i] = (f4){0.f, 0.f, 0.f, 0.f};
    {
      const int abase = r0 * APITCH + 36 * s;  // 36*(k0>>5) = 36s
#pragma unroll
      for (int q = 0; q < 8; ++q) {
        const int ai = abase + 4 * q;
        f4 a0 = *(const f4*)&a_s[ai];
        f4 a1 = *(const f4*)&a_s[ai + APITCH];
        f4 a2 = *(const f4*)&a_s[ai + 2 * APITCH];
        f4 a3 = *(const f4*)&a_s[ai + 3 * APITCH];
        const f4 w0 = wreg[4 * q], w1 = wreg[4 * q + 1];
        const f4 w2 = wreg[4 * q + 2], w3 = wreg[4 * q + 3];
        acc[0] += a0.x * w0 + a0.y * w1 + a0.z * w2 + a0.w * w3;
        acc[1] += a1.x * w0 + a1.y * w1 + a1.z * w2 + a1.w * w3;
        acc[2] += a2.x * w0 + a2.y * w1 + a2.z * w2 + a2.w * w3;
        acc[3] += a3.x * w0 + a3.y * w1 + a3.z * w2 + a3.w * w3;
      }
    }
    // ---- 4. write partials red2[s*264 + out], b128 (de-aliased: no
    //         pre-barrier needed; prev-phase finalize reads were sealed by
    //         the drain barrier) ----
#pragma unroll
    for (int i = 0; i < 4; ++i)
      *(f4*)&red2[s * RPITCH + (r0 + i) * 32 + cb] = acc[i];
    __syncthreads();  // B1: all partials visible
    // ---- 5. finalize: 256 threads, sum 32 partials, bias+act, store ----
    if (tid < 256) {
      float sum = 0.f;
#pragma unroll
      for (int z = 0; z < 32; ++z) sum += red2[z * RPITCH + tid];
      if (p == 0) {
        float v = sum + xpre;
        llc_store(slotw + fyi, LRELU(v));
      } else if (p < 3) {
        float v = sum + (p == 1 ? bh0r : bh1r);
        llc_store(slotw + fyi, LRELU(v));
      } else {
        float yn = ypre + sum + bor;  // ybuf prefetched at phase start
        ybuf[fyi] = yn;
        llc_store(slotw + fyi, yn);  // y is next p0's A
        yout = yn;                   // out[] store deferred past flag post
        oidx = ((size_t)frow * T + t) * U + fu;
        do_out = 1;
      }
    }
    // ---- 6. drain: exchange stores at LLC before the flag post ----
    asm volatile("" ::: "memory");
    __builtin_amdgcn_s_waitcnt(0);
    __syncthreads();
    // ---- 7. W prefetch for P+1 (single reload site; overlaps post + poll
    //         + next stage) ----
    if (P < 4 * T - 1) {
      const float* wp = wbase(P + 1);
#pragma unroll
      for (int j = 0; j < 32; ++j) wreg[j] = *(const f4*)(wp + (size_t)j * U);
    }
    // ---- 8. release: per-producer flag store (no RMW serialization) ----
    if (tid == 0) llc_flag_store(myflag, (unsigned)(P + 1));
    // ---- 9. deferred p3 out-store (HBM ack off the flag critical path;
    //         next phase's waitcnt(0) absorbs it) ----
    if (do_out) out[oidx] = yout;
  }
}

extern "C" void kernel_launch(void* const* d_in, const int* in_sizes, int n_in,
                              void* d_out, int out_size, void* d_ws,
                              size_t ws_size, hipStream_t stream) {
  const int* x = (const int*)d_in[0];
  const float* emb = (const float*)d_in[1];
  const float* w_y = (const float*)d_in[2];
  const float* w_x = (const float*)d_in[3];
  const float* b_in = (const float*)d_in[4];
  const float* w_h = (const float*)d_in[5];
  const float* b_h = (const float*)d_in[6];
  const float* w_out = (const float*)d_in[7];
  const float* b_out = (const float*)d_in[8];
  const float* h0 = (const float*)d_in[9];
  float* out = (float*)d_out;

  // workspace (floats): xproj | slots[2] | ybuf | flags
  float* ws = (float*)d_ws;
  float* xpb = ws;                         // T*B*U
  float* slots = xpb + (size_t)T * B * U;  // 2*BU
  float* ybuf = slots + 2 * (size_t)BU;    // BU
  unsigned* flags = (unsigned*)(ybuf + (size_t)BU);  // 256 uints (512 zeroed)

  k_init<<<256, 256, 0, stream>>>(slots + (size_t)BU, ybuf, h0, flags);
  dim3 g1(256, 16);
  k_xproj<<<g1, 256, 0, stream>>>(x, emb, w_x, b_in, xpb);

  void* args[] = {&xpb,   &w_y, &w_h,   &b_h,  &w_out,
                  &b_out, &out, &slots, &ybuf, &flags};
  hipLaunchCooperativeKernel((void*)k_seq, dim3(256), dim3(512), args, 0u,
                             stream);
}